// Round 1
// baseline (1025.216 us; speedup 1.0000x reference)
//
#include <hip/hip_runtime.h>
#include <math.h>

// Swin block: B=8, C=256, H=W=128, WS=8, SS=4, NH=8, dh=32
// 2048 windows x 64 tokens x 256 ch. All matmuls via mfma_f32_16x16x32_bf16.

#define LDH 264   // bf16 row stride for [64][256] tiles (16B-aligned rows, stride%32w==4)
#define LDVT 72   // bf16 row stride for vT [256][64]
#define LDP 72    // bf16 row stride for P [64][64]
#define LDW 257   // fp32 row stride for win stage [64][256] (conflict-free columns)
#define T64 64

typedef __attribute__((ext_vector_type(8))) short bf16x8;
typedef __attribute__((ext_vector_type(4))) float f32x4;

__device__ __forceinline__ float bf2f(short s){
  union { unsigned u; float f; } cv;
  cv.u = ((unsigned)(unsigned short)s) << 16;
  return cv.f;
}
__device__ __forceinline__ short f2bf(float f){
  union { float f; unsigned u; } cv; cv.f = f;
  unsigned r = (cv.u + 0x7FFFu + ((cv.u >> 16) & 1u)) >> 16;  // RNE
  return (short)r;
}
__device__ __forceinline__ float gelu_f(float x){
  return 0.5f * x * (1.0f + erff(x * 0.7071067811865475f));
}

// ---------------- kernel 0: fp32 -> bf16 weight convert ----------------
__global__ void wconv_kernel(const float* __restrict__ src, short* __restrict__ dst, int n){
  int i = blockIdx.x * 256 + threadIdx.x;
  if (i < n) dst[i] = f2bf(src[i]);
}

// ---------------- kernel 1: LN1 + QKV + attention + out-proj + residual ----------------
// LDS plan (bytes):
//   [0      .. 33792)  h bf16 [64][264]          -> reused as o after QKV
//   [33792  .. 67584)  q bf16 [64][264]           } phase1: win fp32 [64][257] (65792B)
//   [67584  ..101376)  k bf16 [64][264]           } attn: P buffers 4x[64][72] (36864B from 33792)
//   [101376 ..138240)  vT bf16 [256][72]
//   [138240 ..140288)  reduce scratch 2x[256] f32
#define K1_OFF_H   0
#define K1_OFF_Q   33792
#define K1_OFF_K   67584
#define K1_OFF_VT  101376
#define K1_OFF_RED 138240
#define K1_SMEM    140288

__global__ __launch_bounds__(256, 1)
void swin_attn_kernel(const float* __restrict__ x,
                      const float* __restrict__ ln1w, const float* __restrict__ ln1b,
                      const float* __restrict__ inb,  const float* __restrict__ outb,
                      const short* __restrict__ wqkv, const short* __restrict__ wout,
                      short* __restrict__ win2)
{
  __shared__ char smem[K1_SMEM];
  short* sh_h   = (short*)(smem + K1_OFF_H);
  short* sh_q   = (short*)(smem + K1_OFF_Q);
  short* sh_k   = (short*)(smem + K1_OFF_K);
  short* sh_vt  = (short*)(smem + K1_OFF_VT);
  float* sh_win = (float*)(smem + K1_OFF_Q);
  float* red_s  = (float*)(smem + K1_OFF_RED);
  float* red_q2 = red_s + 256;

  const int tid = threadIdx.x;
  const int wv  = tid >> 6;
  const int ln  = tid & 63;
  const int rowa = ln & 15;   // MFMA A/B row-within-tile, also D col
  const int kg   = ln >> 4;   // MFMA k-group

  const int wi = blockIdx.x;
  const int b  = wi >> 8;
  const int wh = (wi >> 4) & 15;
  const int ww = wi & 15;

  // lane <-> token mapping for staging (token = lane)
  const int hh = (wh*8 + (ln >> 3) + 4) & 127;   // roll(-4): rolled[i]=orig[(i+4)%128]
  const int wc = (ww*8 + (ln & 7) + 4) & 127;
  const int offhw = hh*128 + wc;
  const int xbase = b << 22;   // b * 256 * 16384

  // ---- phase 1: stage shifted window, fp32 ----
  for (int c0 = 0; c0 < 256; c0 += 4){
    int c = c0 + wv;
    sh_win[ln*LDW + c] = x[xbase + (c << 14) + offhw];
  }
  __syncthreads();

  // ---- phase 2: LN1 -> h bf16 ----
  {
    float s = 0.f, sq = 0.f;
    const int cbeg = wv*64;
    for (int c = cbeg; c < cbeg+64; ++c){
      float v = sh_win[ln*LDW + c];
      s += v; sq += v*v;
    }
    red_s[cbeg + ln]  = s;
    red_q2[cbeg + ln] = sq;
    __syncthreads();
    float sum = red_s[ln] + red_s[64+ln] + red_s[128+ln] + red_s[192+ln];
    float ssq = red_q2[ln] + red_q2[64+ln] + red_q2[128+ln] + red_q2[192+ln];
    float mean = sum * 0.00390625f;
    float var  = ssq * 0.00390625f - mean*mean;
    float rstd = rsqrtf(var + 1e-5f);
    for (int c = cbeg; c < cbeg+64; ++c){
      float v = (sh_win[ln*LDW + c] - mean) * rstd * ln1w[c] + ln1b[c];
      sh_h[ln*LDH + c] = f2bf(v);
    }
  }
  __syncthreads();

  // ---- phase 3: QKV GEMM [64x256]x[256x768]; wave wv owns cols wv*64.. of each of q/k/v ----
  for (int ch = 0; ch < 3; ++ch){
    const int gcb = ch*256 + wv*64;
    f32x4 acc[4][4];
    #pragma unroll
    for (int mt=0;mt<4;++mt)
      #pragma unroll
      for (int nt=0;nt<4;++nt)
        acc[mt][nt] = (f32x4){0.f,0.f,0.f,0.f};
    for (int kt = 0; kt < 8; ++kt){
      bf16x8 av[4], bv[4];
      #pragma unroll
      for (int mt=0;mt<4;++mt)
        av[mt] = *(const bf16x8*)&sh_h[(mt*16+rowa)*LDH + kt*32 + kg*8];
      #pragma unroll
      for (int nt=0;nt<4;++nt)
        bv[nt] = *(const bf16x8*)&wqkv[(gcb + nt*16 + rowa)*256 + kt*32 + kg*8];
      #pragma unroll
      for (int mt=0;mt<4;++mt)
        #pragma unroll
        for (int nt=0;nt<4;++nt)
          acc[mt][nt] = __builtin_amdgcn_mfma_f32_16x16x32_bf16(av[mt], bv[nt], acc[mt][nt], 0, 0, 0);
    }
    #pragma unroll
    for (int nt=0;nt<4;++nt){
      const int gcol = gcb + nt*16 + rowa;
      const float bias = inb[gcol];
      const int lcol = wv*64 + nt*16 + rowa;
      #pragma unroll
      for (int mt=0;mt<4;++mt){
        #pragma unroll
        for (int i=0;i<4;++i){
          const int row = mt*16 + kg*4 + i;
          const short v = f2bf(acc[mt][nt][i] + bias);
          if (ch == 0)      sh_q[row*LDH + lcol] = v;
          else if (ch == 1) sh_k[row*LDH + lcol] = v;
          else              sh_vt[lcol*LDVT + row] = v;   // V transposed: [channel][token]
        }
      }
    }
  }
  __syncthreads();

  // ---- phase 4: attention; wave wv owns heads 2wv, 2wv+1; S for both first (frees q,k) ----
  f32x4 sacc[2][4][4];
  #pragma unroll
  for (int hd=0; hd<2; ++hd)
    #pragma unroll
    for (int mt=0;mt<4;++mt)
      #pragma unroll
      for (int nt=0;nt<4;++nt)
        sacc[hd][mt][nt] = (f32x4){0.f,0.f,0.f,0.f};
  #pragma unroll
  for (int hd=0; hd<2; ++hd){
    const int kb = (2*wv + hd)*32;
    bf16x8 av[4], bv[4];
    #pragma unroll
    for (int mt=0;mt<4;++mt)
      av[mt] = *(const bf16x8*)&sh_q[(mt*16+rowa)*LDH + kb + kg*8];
    #pragma unroll
    for (int nt=0;nt<4;++nt)
      bv[nt] = *(const bf16x8*)&sh_k[(nt*16+rowa)*LDH + kb + kg*8];
    #pragma unroll
    for (int mt=0;mt<4;++mt)
      #pragma unroll
      for (int nt=0;nt<4;++nt)
        sacc[hd][mt][nt] = __builtin_amdgcn_mfma_f32_16x16x32_bf16(av[mt], bv[nt], sacc[hd][mt][nt], 0, 0, 0);
  }
  __syncthreads();   // all waves done with q,k -> region becomes P buffers

  short* sh_p = (short*)(smem + K1_OFF_Q) + wv * (T64 * LDP);  // wave-private [64][72]
  short* sh_o = sh_h;                                          // h dead -> o
  const float scale = 0.1767766952966369f;  // 1/sqrt(32)

  #pragma unroll
  for (int hd=0; hd<2; ++hd){
    const int kb = (2*wv + hd)*32;
    // softmax over rows (row = query); cols spread over 16 lanes x 4 tiles
    #pragma unroll
    for (int mt=0;mt<4;++mt){
      #pragma unroll
      for (int i=0;i<4;++i){
        float v0 = sacc[hd][mt][0][i]*scale;
        float v1 = sacc[hd][mt][1][i]*scale;
        float v2 = sacc[hd][mt][2][i]*scale;
        float v3 = sacc[hd][mt][3][i]*scale;
        float mx = fmaxf(fmaxf(v0,v1), fmaxf(v2,v3));
        #pragma unroll
        for (int d=1; d<16; d<<=1) mx = fmaxf(mx, __shfl_xor(mx, d, 64));
        v0 = __expf(v0-mx); v1 = __expf(v1-mx); v2 = __expf(v2-mx); v3 = __expf(v3-mx);
        float sm = v0+v1+v2+v3;
        #pragma unroll
        for (int d=1; d<16; d<<=1) sm += __shfl_xor(sm, d, 64);
        const float inv = 1.f / sm;
        const int row = mt*16 + kg*4 + i;
        sh_p[row*LDP +  0 + rowa] = f2bf(v0*inv);
        sh_p[row*LDP + 16 + rowa] = f2bf(v1*inv);
        sh_p[row*LDP + 32 + rowa] = f2bf(v2*inv);
        sh_p[row*LDP + 48 + rowa] = f2bf(v3*inv);
      }
    }
    asm volatile("s_waitcnt lgkmcnt(0)" ::: "memory");  // wave-private P write->read
    // PV: [64x64]x[64x32], K split in 2
    f32x4 oacc[4][2];
    #pragma unroll
    for (int mt=0;mt<4;++mt){ oacc[mt][0]=(f32x4){0.f,0.f,0.f,0.f}; oacc[mt][1]=(f32x4){0.f,0.f,0.f,0.f}; }
    #pragma unroll
    for (int kt2=0; kt2<2; ++kt2){
      bf16x8 av[4], bv[2];
      #pragma unroll
      for (int mt=0;mt<4;++mt)
        av[mt] = *(const bf16x8*)&sh_p[(mt*16+rowa)*LDP + kt2*32 + kg*8];
      #pragma unroll
      for (int nt=0;nt<2;++nt)
        bv[nt] = *(const bf16x8*)&sh_vt[(kb + nt*16 + rowa)*LDVT + kt2*32 + kg*8];
      #pragma unroll
      for (int mt=0;mt<4;++mt)
        #pragma unroll
        for (int nt=0;nt<2;++nt)
          oacc[mt][nt] = __builtin_amdgcn_mfma_f32_16x16x32_bf16(av[mt], bv[nt], oacc[mt][nt], 0, 0, 0);
    }
    #pragma unroll
    for (int nt=0;nt<2;++nt){
      const int col = kb + nt*16 + rowa;
      #pragma unroll
      for (int mt=0;mt<4;++mt)
        #pragma unroll
        for (int i=0;i<4;++i)
          sh_o[(mt*16 + kg*4 + i)*LDH + col] = f2bf(oacc[mt][nt][i]);
    }
    asm volatile("s_waitcnt lgkmcnt(0)" ::: "memory");  // P reads done before next head reuses it
  }
  __syncthreads();

  // ---- phase 5: re-stage win fp32 for residual (over dead q/k/P region) ----
  for (int c0 = 0; c0 < 256; c0 += 4){
    int c = c0 + wv;
    sh_win[ln*LDW + c] = x[xbase + (c << 14) + offhw];
  }
  __syncthreads();

  // ---- phase 6: out-proj [64x256]x[256x256] + bias + residual -> win2 (bf16) ----
  {
    f32x4 acc[4][4];
    #pragma unroll
    for (int mt=0;mt<4;++mt)
      #pragma unroll
      for (int nt=0;nt<4;++nt)
        acc[mt][nt] = (f32x4){0.f,0.f,0.f,0.f};
    for (int kt=0; kt<8; ++kt){
      bf16x8 av[4], bv[4];
      #pragma unroll
      for (int mt=0;mt<4;++mt)
        av[mt] = *(const bf16x8*)&sh_o[(mt*16+rowa)*LDH + kt*32 + kg*8];
      #pragma unroll
      for (int nt=0;nt<4;++nt)
        bv[nt] = *(const bf16x8*)&wout[(wv*64 + nt*16 + rowa)*256 + kt*32 + kg*8];
      #pragma unroll
      for (int mt=0;mt<4;++mt)
        #pragma unroll
        for (int nt=0;nt<4;++nt)
          acc[mt][nt] = __builtin_amdgcn_mfma_f32_16x16x32_bf16(av[mt], bv[nt], acc[mt][nt], 0, 0, 0);
    }
    #pragma unroll
    for (int nt=0;nt<4;++nt){
      const int col = wv*64 + nt*16 + rowa;
      const float bias = outb[col];
      #pragma unroll
      for (int mt=0;mt<4;++mt){
        #pragma unroll
        for (int i=0;i<4;++i){
          const int row = mt*16 + kg*4 + i;
          float v = acc[mt][nt][i] + bias + sh_win[row*LDW + col];
          win2[(wi*64 + row)*256 + col] = f2bf(v);
        }
      }
    }
  }
}

// ---------------- kernel 2: LN2 + MLP + residual + NCHW scatter ----------------
#define K2_OFF_S   0        // win2 stage / m_chunk  [64][264] bf16
#define K2_OFF_H   33792    // h2 [64][264] bf16
#define K2_OFF_RED 67584
#define K2_SMEM    69632

__global__ __launch_bounds__(256, 2)
void swin_mlp_kernel(const short* __restrict__ win2,
                     const float* __restrict__ ln2w, const float* __restrict__ ln2b,
                     const float* __restrict__ b1,   const float* __restrict__ b2,
                     const short* __restrict__ w1,   const short* __restrict__ w2,
                     float* __restrict__ out)
{
  __shared__ char smem[K2_SMEM];
  short* sh_s   = (short*)(smem + K2_OFF_S);
  short* sh_h   = (short*)(smem + K2_OFF_H);
  float* red_s  = (float*)(smem + K2_OFF_RED);
  float* red_q2 = red_s + 256;

  const int tid = threadIdx.x;
  const int wv  = tid >> 6;
  const int ln  = tid & 63;
  const int rowa = ln & 15;
  const int kg   = ln >> 4;
  const int wi = blockIdx.x;
  const int wbase = wi * (64*256);

  // stage win2 bf16 (coalesced 16B loads)
  #pragma unroll
  for (int j = 0; j < 8; ++j){
    int idx = tid + j*256;
    int t = idx >> 5, c8 = idx & 31;
    *(bf16x8*)&sh_s[t*LDH + c8*8] = *(const bf16x8*)&win2[wbase + t*256 + c8*8];
  }
  __syncthreads();

  // LN2 -> h2 bf16
  {
    float s = 0.f, sq = 0.f;
    const int cbeg = wv*64;
    for (int c = cbeg; c < cbeg+64; ++c){
      float v = bf2f(sh_s[ln*LDH + c]);
      s += v; sq += v*v;
    }
    red_s[cbeg + ln]  = s;
    red_q2[cbeg + ln] = sq;
    __syncthreads();
    float sum = red_s[ln] + red_s[64+ln] + red_s[128+ln] + red_s[192+ln];
    float ssq = red_q2[ln] + red_q2[64+ln] + red_q2[128+ln] + red_q2[192+ln];
    float mean = sum * 0.00390625f;
    float var  = ssq * 0.00390625f - mean*mean;
    float rstd = rsqrtf(var + 1e-5f);
    for (int c = cbeg; c < cbeg+64; ++c){
      float v = (bf2f(sh_s[ln*LDH + c]) - mean) * rstd * ln2w[c] + ln2b[c];
      sh_h[ln*LDH + c] = f2bf(v);
    }
  }
  __syncthreads();

  // MLP: 4 chunks of 256 hidden cols; GEMM1+GELU -> m_chunk LDS -> GEMM2 accumulate
  f32x4 acc2[4][4];
  #pragma unroll
  for (int mt=0;mt<4;++mt)
    #pragma unroll
    for (int nt=0;nt<4;++nt)
      acc2[mt][nt] = (f32x4){0.f,0.f,0.f,0.f};

  for (int chk = 0; chk < 4; ++chk){
    f32x4 acc1[4][4];
    #pragma unroll
    for (int mt=0;mt<4;++mt)
      #pragma unroll
      for (int nt=0;nt<4;++nt)
        acc1[mt][nt] = (f32x4){0.f,0.f,0.f,0.f};
    for (int kt=0; kt<8; ++kt){
      bf16x8 av[4], bv[4];
      #pragma unroll
      for (int mt=0;mt<4;++mt)
        av[mt] = *(const bf16x8*)&sh_h[(mt*16+rowa)*LDH + kt*32 + kg*8];
      #pragma unroll
      for (int nt=0;nt<4;++nt)
        bv[nt] = *(const bf16x8*)&w1[(chk*256 + wv*64 + nt*16 + rowa)*256 + kt*32 + kg*8];
      #pragma unroll
      for (int mt=0;mt<4;++mt)
        #pragma unroll
        for (int nt=0;nt<4;++nt)
          acc1[mt][nt] = __builtin_amdgcn_mfma_f32_16x16x32_bf16(av[mt], bv[nt], acc1[mt][nt], 0, 0, 0);
    }
    __syncthreads();   // previous chunk's GEMM2 reads of sh_s complete
    #pragma unroll
    for (int nt=0;nt<4;++nt){
      const int n = chk*256 + wv*64 + nt*16 + rowa;
      const float bias = b1[n];
      const int lcol = wv*64 + nt*16 + rowa;
      #pragma unroll
      for (int mt=0;mt<4;++mt)
        #pragma unroll
        for (int i=0;i<4;++i)
          sh_s[(mt*16 + kg*4 + i)*LDH + lcol] = f2bf(gelu_f(acc1[mt][nt][i] + bias));
    }
    __syncthreads();   // m_chunk visible to all waves
    for (int kt=0; kt<8; ++kt){
      bf16x8 av[4], bv[4];
      #pragma unroll
      for (int mt=0;mt<4;++mt)
        av[mt] = *(const bf16x8*)&sh_s[(mt*16+rowa)*LDH + kt*32 + kg*8];
      #pragma unroll
      for (int nt=0;nt<4;++nt)
        bv[nt] = *(const bf16x8*)&w2[(wv*64 + nt*16 + rowa)*1024 + chk*256 + kt*32 + kg*8];
      #pragma unroll
      for (int mt=0;mt<4;++mt)
        #pragma unroll
        for (int nt=0;nt<4;++nt)
          acc2[mt][nt] = __builtin_amdgcn_mfma_f32_16x16x32_bf16(av[mt], bv[nt], acc2[mt][nt], 0, 0, 0);
    }
  }
  __syncthreads();

  // epilogue: + b2 + win2 residual, scatter to NCHW with unshift
  const int b  = wi >> 8;
  const int wh = (wi >> 4) & 15;
  const int ww = wi & 15;
  #pragma unroll
  for (int nt=0;nt<4;++nt){
    const int col = wv*64 + nt*16 + rowa;
    const float bias = b2[col];
    #pragma unroll
    for (int mt=0;mt<4;++mt){
      #pragma unroll
      for (int i=0;i<4;++i){
        const int row = mt*16 + kg*4 + i;
        float v = acc2[mt][nt][i] + bias + bf2f(win2[wbase + row*256 + col]);
        const int r = row >> 3, cw = row & 7;
        const int hh = (wh*8 + r + 4) & 127;
        const int wcc = (ww*8 + cw + 4) & 127;
        out[(((b<<8) + col) << 14) + hh*128 + wcc] = v;
      }
    }
  }
}

// ---------------- launch ----------------
extern "C" void kernel_launch(void* const* d_in, const int* in_sizes, int n_in,
                              void* d_out, int out_size, void* d_ws, size_t ws_size,
                              hipStream_t stream) {
  (void)in_sizes; (void)n_in; (void)out_size; (void)ws_size;
  const float* x    = (const float*)d_in[0];
  const float* ln1w = (const float*)d_in[1];
  const float* ln1b = (const float*)d_in[2];
  const float* inw  = (const float*)d_in[3];
  const float* inb  = (const float*)d_in[4];
  const float* outw = (const float*)d_in[5];
  const float* outb = (const float*)d_in[6];
  const float* ln2w = (const float*)d_in[7];
  const float* ln2b = (const float*)d_in[8];
  const float* w1f  = (const float*)d_in[9];
  const float* b1   = (const float*)d_in[10];
  const float* w2f  = (const float*)d_in[11];
  const float* b2   = (const float*)d_in[12];
  float* out = (float*)d_out;

  short* ws    = (short*)d_ws;
  short* wqkv  = ws;            // 768*256
  short* wout  = ws + 196608;   // 256*256
  short* w1b   = ws + 262144;   // 1024*256
  short* w2b   = ws + 524288;   // 256*1024
  short* win2  = ws + 786432;   // 2048*64*256 bf16

  hipLaunchKernelGGL(wconv_kernel, dim3(768),  dim3(256), 0, stream, inw,  wqkv, 196608);
  hipLaunchKernelGGL(wconv_kernel, dim3(256),  dim3(256), 0, stream, outw, wout, 65536);
  hipLaunchKernelGGL(wconv_kernel, dim3(1024), dim3(256), 0, stream, w1f,  w1b,  262144);
  hipLaunchKernelGGL(wconv_kernel, dim3(1024), dim3(256), 0, stream, w2f,  w2b,  262144);

  hipLaunchKernelGGL(swin_attn_kernel, dim3(2048), dim3(256), 0, stream,
                     x, ln1w, ln1b, inb, outb, wqkv, wout, win2);
  hipLaunchKernelGGL(swin_mlp_kernel, dim3(2048), dim3(256), 0, stream,
                     win2, ln2w, ln2b, b1, b2, w1b, w2b, out);
}

// Round 2
// 835.395 us; speedup vs baseline: 1.2272x; 1.2272x over previous
//
#include <hip/hip_runtime.h>
#include <math.h>

// Swin block: B=8, C=256, H=W=128, WS=8, SS=4, NH=8, dh=32
// 2048 windows x 64 tokens x 256 ch. All matmuls via mfma_f32_16x16x32_bf16.

#define LDH 264   // bf16 row stride for [64][256] tiles (rows 528B: 16B-aligned, 4r-bank spread)
#define LDS_S 40  // bf16 row stride for per-wave [64][40] slots (rows 80B)

typedef __attribute__((ext_vector_type(8))) short bf16x8;
typedef __attribute__((ext_vector_type(4))) float f32x4;

__device__ __forceinline__ float bf2f(short s){
  union { unsigned u; float f; } cv;
  cv.u = ((unsigned)(unsigned short)s) << 16;
  return cv.f;
}
__device__ __forceinline__ short f2bf(float f){
  union { float f; unsigned u; } cv; cv.f = f;
  unsigned r = (cv.u + 0x7FFFu + ((cv.u >> 16) & 1u)) >> 16;  // RNE
  return (short)r;
}
__device__ __forceinline__ float gelu_f(float x){
  return 0.5f * x * (1.0f + erff(x * 0.7071067811865475f));
}

// ---------------- kernel 0: fp32 -> bf16 weight convert ----------------
__global__ void wconv_kernel(const float* __restrict__ src, short* __restrict__ dst, int n){
  int i = blockIdx.x * 256 + threadIdx.x;
  if (i < n) dst[i] = f2bf(src[i]);
}

// [64x256] @ [256 x 32] GEMM helper: A from sh_h, B rows wrowbase.. of w (bf16 [.][256])
__device__ __forceinline__ void gemm_h_w32(const short* __restrict__ sh_h,
                                           const short* __restrict__ w, int wrowbase,
                                           int rowa, int kg, f32x4 acc[4][2]){
  #pragma unroll
  for (int kt = 0; kt < 8; ++kt){
    bf16x8 av[4], bw[2];
    #pragma unroll
    for (int mt=0;mt<4;++mt)
      av[mt] = *(const bf16x8*)&sh_h[(mt*16+rowa)*LDH + kt*32 + kg*8];
    #pragma unroll
    for (int nt=0;nt<2;++nt)
      bw[nt] = *(const bf16x8*)&w[(wrowbase + nt*16 + rowa)*256 + kt*32 + kg*8];
    #pragma unroll
    for (int mt=0;mt<4;++mt)
      #pragma unroll
      for (int nt=0;nt<2;++nt)
        acc[mt][nt] = __builtin_amdgcn_mfma_f32_16x16x32_bf16(av[mt], bw[nt], acc[mt][nt], 0, 0, 0);
  }
}

// ---------------- kernel 1: LN1 + QKV + attention + out-proj + residual ----------------
// LDS (76800 B -> 2 blocks/CU):
//   [0,     33792)  h bf16 [64][264]  -> reused as o after both heads done
//   [33792, 74752)  per-wave 10240 B: slotA [64][40] (q -> P chunks), slotB (k -> vT [32][40])
//   [74752, 76800)  reduce scratch 2x[256] f32
#define K1_OFF_WV  33792
#define K1_OFF_RED 74752
#define K1_SMEM    76800

__global__ __launch_bounds__(256, 2)
void swin_attn_kernel(const float* __restrict__ x,
                      const float* __restrict__ ln1w, const float* __restrict__ ln1b,
                      const float* __restrict__ inb,  const float* __restrict__ outb,
                      const short* __restrict__ wqkv, const short* __restrict__ wout,
                      short* __restrict__ win2)
{
  __shared__ char smem[K1_SMEM];
  short* sh_h   = (short*)smem;
  float* red_s  = (float*)(smem + K1_OFF_RED);
  float* red_q2 = red_s + 256;

  const int tid = threadIdx.x;
  const int wv  = tid >> 6;
  const int ln  = tid & 63;
  const int rowa = ln & 15;   // MFMA A/B row-within-tile, also D col
  const int kg   = ln >> 4;   // MFMA k-group

  short* slotA = (short*)(smem + K1_OFF_WV) + wv*5120;  // [64][40]
  short* slotB = slotA + 2560;                          // [64][40]

  const int wi = blockIdx.x;
  const int b  = wi >> 8;
  const int wh = (wi >> 4) & 15;
  const int ww = wi & 15;

  const int hh = (wh*8 + (ln >> 3) + 4) & 127;   // roll(-4): rolled[i]=orig[(i+4)%128]
  const int wc = (ww*8 + (ln & 7) + 4) & 127;
  const int offhw = hh*128 + wc;
  const int xbase = b << 22;   // b * 256 * 16384

  // ---- LN1: thread (wv,ln) owns channels wv*64.. of token ln; values held in regs ----
  {
    const int cbeg = wv*64;
    float vals[64];
    float s = 0.f, sq = 0.f;
    #pragma unroll
    for (int j = 0; j < 64; ++j){
      float v = x[xbase + ((cbeg + j) << 14) + offhw];
      vals[j] = v; s += v; sq += v*v;
    }
    red_s[cbeg + ln]  = s;
    red_q2[cbeg + ln] = sq;
    __syncthreads();
    float sum = red_s[ln] + red_s[64+ln] + red_s[128+ln] + red_s[192+ln];
    float ssq = red_q2[ln] + red_q2[64+ln] + red_q2[128+ln] + red_q2[192+ln];
    float mean = sum * 0.00390625f;
    float var  = ssq * 0.00390625f - mean*mean;
    float rstd = rsqrtf(var + 1e-5f);
    #pragma unroll
    for (int j = 0; j < 64; ++j){
      const int c = cbeg + j;
      sh_h[ln*LDH + c] = f2bf((vals[j] - mean) * rstd * ln1w[c] + ln1b[c]);
    }
  }
  __syncthreads();

  // ---- per-wave, per-head attention; wave wv owns heads 2wv, 2wv+1 ----
  const float scale = 0.1767766952966369f;  // 1/sqrt(32)
  f32x4 oacc[4][4];
  #pragma unroll
  for (int mt=0;mt<4;++mt)
    #pragma unroll
    for (int j=0;j<4;++j)
      oacc[mt][j] = (f32x4){0.f,0.f,0.f,0.f};

  #pragma unroll
  for (int hd = 0; hd < 2; ++hd){
    const int hc = (2*wv + hd) * 32;   // global channel base of this head

    // q -> slotA
    {
      f32x4 accq[4][2];
      #pragma unroll
      for (int mt=0;mt<4;++mt){ accq[mt][0]=(f32x4){0,0,0,0}; accq[mt][1]=(f32x4){0,0,0,0}; }
      gemm_h_w32(sh_h, wqkv, 0*256 + hc, rowa, kg, accq);
      #pragma unroll
      for (int nt=0;nt<2;++nt){
        const float bias = inb[hc + nt*16 + rowa];
        #pragma unroll
        for (int mt=0;mt<4;++mt)
          #pragma unroll
          for (int i=0;i<4;++i)
            slotA[(mt*16 + kg*4 + i)*LDS_S + nt*16 + rowa] = f2bf(accq[mt][nt][i] + bias);
      }
    }
    // k -> slotB
    {
      f32x4 acck[4][2];
      #pragma unroll
      for (int mt=0;mt<4;++mt){ acck[mt][0]=(f32x4){0,0,0,0}; acck[mt][1]=(f32x4){0,0,0,0}; }
      gemm_h_w32(sh_h, wqkv, 1*256 + hc, rowa, kg, acck);
      #pragma unroll
      for (int nt=0;nt<2;++nt){
        const float bias = inb[256 + hc + nt*16 + rowa];
        #pragma unroll
        for (int mt=0;mt<4;++mt)
          #pragma unroll
          for (int i=0;i<4;++i)
            slotB[(mt*16 + kg*4 + i)*LDS_S + nt*16 + rowa] = f2bf(acck[mt][nt][i] + bias);
      }
    }

    // S = q @ k^T  (K=32, one k-step)
    f32x4 sacc[4][4];
    #pragma unroll
    for (int mt=0;mt<4;++mt)
      #pragma unroll
      for (int nt=0;nt<4;++nt)
        sacc[mt][nt] = (f32x4){0.f,0.f,0.f,0.f};
    {
      bf16x8 aq[4], bk[4];
      #pragma unroll
      for (int mt=0;mt<4;++mt)
        aq[mt] = *(const bf16x8*)&slotA[(mt*16+rowa)*LDS_S + kg*8];
      #pragma unroll
      for (int nt=0;nt<4;++nt)
        bk[nt] = *(const bf16x8*)&slotB[(nt*16+rowa)*LDS_S + kg*8];
      #pragma unroll
      for (int mt=0;mt<4;++mt)
        #pragma unroll
        for (int nt=0;nt<4;++nt)
          sacc[mt][nt] = __builtin_amdgcn_mfma_f32_16x16x32_bf16(aq[mt], bk[nt], sacc[mt][nt], 0, 0, 0);
    }

    // v -> vT in slotB (k dead after S reads; same-wave DS ordering keeps this safe)
    {
      f32x4 accv[4][2];
      #pragma unroll
      for (int mt=0;mt<4;++mt){ accv[mt][0]=(f32x4){0,0,0,0}; accv[mt][1]=(f32x4){0,0,0,0}; }
      gemm_h_w32(sh_h, wqkv, 2*256 + hc, rowa, kg, accv);
      #pragma unroll
      for (int nt=0;nt<2;++nt){
        const float bias = inb[512 + hc + nt*16 + rowa];
        #pragma unroll
        for (int mt=0;mt<4;++mt)
          #pragma unroll
          for (int i=0;i<4;++i)
            slotB[(nt*16 + rowa)*LDS_S + mt*16 + kg*4 + i] = f2bf(accv[mt][nt][i] + bias);  // [ch][tok]
      }
    }

    // softmax over kv for each q-row; normalized probs back into sacc (fp32)
    #pragma unroll
    for (int mt=0;mt<4;++mt){
      #pragma unroll
      for (int i=0;i<4;++i){
        float v0 = sacc[mt][0][i]*scale;
        float v1 = sacc[mt][1][i]*scale;
        float v2 = sacc[mt][2][i]*scale;
        float v3 = sacc[mt][3][i]*scale;
        float mx = fmaxf(fmaxf(v0,v1), fmaxf(v2,v3));
        #pragma unroll
        for (int d=1; d<16; d<<=1) mx = fmaxf(mx, __shfl_xor(mx, d, 64));
        v0 = __expf(v0-mx); v1 = __expf(v1-mx); v2 = __expf(v2-mx); v3 = __expf(v3-mx);
        float sm = v0+v1+v2+v3;
        #pragma unroll
        for (int d=1; d<16; d<<=1) sm += __shfl_xor(sm, d, 64);
        const float inv = 1.f / sm;
        sacc[mt][0][i] = v0*inv; sacc[mt][1][i] = v1*inv;
        sacc[mt][2][i] = v2*inv; sacc[mt][3][i] = v3*inv;
      }
    }

    // PV in two kv-chunks of 32, P chunk through slotA (q dead)
    #pragma unroll
    for (int ck=0; ck<2; ++ck){
      #pragma unroll
      for (int ntl=0; ntl<2; ++ntl)
        #pragma unroll
        for (int mt=0;mt<4;++mt)
          #pragma unroll
          for (int i=0;i<4;++i)
            slotA[(mt*16 + kg*4 + i)*LDS_S + ntl*16 + rowa] = f2bf(sacc[mt][2*ck+ntl][i]);
      bf16x8 ap[4], bv[2];
      #pragma unroll
      for (int mt=0;mt<4;++mt)
        ap[mt] = *(const bf16x8*)&slotA[(mt*16+rowa)*LDS_S + kg*8];
      #pragma unroll
      for (int nt=0;nt<2;++nt)
        bv[nt] = *(const bf16x8*)&slotB[(nt*16+rowa)*LDS_S + kg*8];
      #pragma unroll
      for (int mt=0;mt<4;++mt)
        #pragma unroll
        for (int nt=0;nt<2;++nt)
          oacc[mt][hd*2+nt] = __builtin_amdgcn_mfma_f32_16x16x32_bf16(ap[mt], bv[nt], oacc[mt][hd*2+nt], 0, 0, 0);
    }
  }

  __syncthreads();   // all waves done with h -> region becomes o

  // o (cols wv*64 + j*16 + rowa) into R0
  #pragma unroll
  for (int j=0;j<4;++j){
    const int col = wv*64 + j*16 + rowa;
    #pragma unroll
    for (int mt=0;mt<4;++mt)
      #pragma unroll
      for (int i=0;i<4;++i)
        sh_h[(mt*16 + kg*4 + i)*LDH + col] = f2bf(oacc[mt][j][i]);
  }
  __syncthreads();

  // ---- out-proj [64x256]x[256x256] + bias + residual(from global x) -> win2 ----
  {
    f32x4 acc[4][4];
    #pragma unroll
    for (int mt=0;mt<4;++mt)
      #pragma unroll
      for (int nt=0;nt<4;++nt)
        acc[mt][nt] = (f32x4){0.f,0.f,0.f,0.f};
    for (int kt=0; kt<8; ++kt){
      bf16x8 av[4], bw[4];
      #pragma unroll
      for (int mt=0;mt<4;++mt)
        av[mt] = *(const bf16x8*)&sh_h[(mt*16+rowa)*LDH + kt*32 + kg*8];
      #pragma unroll
      for (int nt=0;nt<4;++nt)
        bw[nt] = *(const bf16x8*)&wout[(wv*64 + nt*16 + rowa)*256 + kt*32 + kg*8];
      #pragma unroll
      for (int mt=0;mt<4;++mt)
        #pragma unroll
        for (int nt=0;nt<4;++nt)
          acc[mt][nt] = __builtin_amdgcn_mfma_f32_16x16x32_bf16(av[mt], bw[nt], acc[mt][nt], 0, 0, 0);
    }
    #pragma unroll
    for (int nt=0;nt<4;++nt){
      const int col = wv*64 + nt*16 + rowa;
      const float bias = outb[col];
      #pragma unroll
      for (int mt=0;mt<4;++mt){
        #pragma unroll
        for (int i=0;i<4;++i){
          const int row = mt*16 + kg*4 + i;
          const int r = row >> 3, cw = row & 7;
          const int hh2 = (wh*8 + r + 4) & 127;
          const int wc2 = (ww*8 + cw + 4) & 127;
          const float res = x[xbase + (col << 14) + hh2*128 + wc2];
          win2[(wi*64 + row)*256 + col] = f2bf(acc[mt][nt][i] + bias + res);
        }
      }
    }
  }
}

// ---------------- kernel 2: LN2 + MLP + residual + NCHW scatter ----------------
#define K2_OFF_S   0        // win2 stage / m_chunk  [64][264] bf16
#define K2_OFF_H   33792    // h2 [64][264] bf16
#define K2_OFF_RED 67584
#define K2_SMEM    69632

__global__ __launch_bounds__(256, 2)
void swin_mlp_kernel(const short* __restrict__ win2,
                     const float* __restrict__ ln2w, const float* __restrict__ ln2b,
                     const float* __restrict__ b1,   const float* __restrict__ b2,
                     const short* __restrict__ w1,   const short* __restrict__ w2,
                     float* __restrict__ out)
{
  __shared__ char smem[K2_SMEM];
  short* sh_s   = (short*)(smem + K2_OFF_S);
  short* sh_h   = (short*)(smem + K2_OFF_H);
  float* red_s  = (float*)(smem + K2_OFF_RED);
  float* red_q2 = red_s + 256;

  const int tid = threadIdx.x;
  const int wv  = tid >> 6;
  const int ln  = tid & 63;
  const int rowa = ln & 15;
  const int kg   = ln >> 4;
  const int wi = blockIdx.x;
  const int wbase = wi * (64*256);

  // stage win2 bf16 (coalesced 16B loads)
  #pragma unroll
  for (int j = 0; j < 8; ++j){
    int idx = tid + j*256;
    int t = idx >> 5, c8 = idx & 31;
    *(bf16x8*)&sh_s[t*LDH + c8*8] = *(const bf16x8*)&win2[wbase + t*256 + c8*8];
  }
  __syncthreads();

  // LN2 -> h2 bf16
  {
    float s = 0.f, sq = 0.f;
    const int cbeg = wv*64;
    for (int c = cbeg; c < cbeg+64; ++c){
      float v = bf2f(sh_s[ln*LDH + c]);
      s += v; sq += v*v;
    }
    red_s[cbeg + ln]  = s;
    red_q2[cbeg + ln] = sq;
    __syncthreads();
    float sum = red_s[ln] + red_s[64+ln] + red_s[128+ln] + red_s[192+ln];
    float ssq = red_q2[ln] + red_q2[64+ln] + red_q2[128+ln] + red_q2[192+ln];
    float mean = sum * 0.00390625f;
    float var  = ssq * 0.00390625f - mean*mean;
    float rstd = rsqrtf(var + 1e-5f);
    for (int c = cbeg; c < cbeg+64; ++c){
      float v = (bf2f(sh_s[ln*LDH + c]) - mean) * rstd * ln2w[c] + ln2b[c];
      sh_h[ln*LDH + c] = f2bf(v);
    }
  }
  __syncthreads();

  // MLP: 4 chunks of 256 hidden cols; GEMM1+GELU -> m_chunk LDS -> GEMM2 accumulate
  f32x4 acc2[4][4];
  #pragma unroll
  for (int mt=0;mt<4;++mt)
    #pragma unroll
    for (int nt=0;nt<4;++nt)
      acc2[mt][nt] = (f32x4){0.f,0.f,0.f,0.f};

  for (int chk = 0; chk < 4; ++chk){
    f32x4 acc1[4][4];
    #pragma unroll
    for (int mt=0;mt<4;++mt)
      #pragma unroll
      for (int nt=0;nt<4;++nt)
        acc1[mt][nt] = (f32x4){0.f,0.f,0.f,0.f};
    for (int kt=0; kt<8; ++kt){
      bf16x8 av[4], bv[4];
      #pragma unroll
      for (int mt=0;mt<4;++mt)
        av[mt] = *(const bf16x8*)&sh_h[(mt*16+rowa)*LDH + kt*32 + kg*8];
      #pragma unroll
      for (int nt=0;nt<4;++nt)
        bv[nt] = *(const bf16x8*)&w1[(chk*256 + wv*64 + nt*16 + rowa)*256 + kt*32 + kg*8];
      #pragma unroll
      for (int mt=0;mt<4;++mt)
        #pragma unroll
        for (int nt=0;nt<4;++nt)
          acc1[mt][nt] = __builtin_amdgcn_mfma_f32_16x16x32_bf16(av[mt], bv[nt], acc1[mt][nt], 0, 0, 0);
    }
    __syncthreads();   // previous chunk's GEMM2 reads of sh_s complete
    #pragma unroll
    for (int nt=0;nt<4;++nt){
      const int n = chk*256 + wv*64 + nt*16 + rowa;
      const float bias = b1[n];
      const int lcol = wv*64 + nt*16 + rowa;
      #pragma unroll
      for (int mt=0;mt<4;++mt)
        #pragma unroll
        for (int i=0;i<4;++i)
          sh_s[(mt*16 + kg*4 + i)*LDH + lcol] = f2bf(gelu_f(acc1[mt][nt][i] + bias));
    }
    __syncthreads();   // m_chunk visible to all waves
    for (int kt=0; kt<8; ++kt){
      bf16x8 av[4], bv[4];
      #pragma unroll
      for (int mt=0;mt<4;++mt)
        av[mt] = *(const bf16x8*)&sh_s[(mt*16+rowa)*LDH + kt*32 + kg*8];
      #pragma unroll
      for (int nt=0;nt<4;++nt)
        bv[nt] = *(const bf16x8*)&w2[(wv*64 + nt*16 + rowa)*1024 + chk*256 + kt*32 + kg*8];
      #pragma unroll
      for (int mt=0;mt<4;++mt)
        #pragma unroll
        for (int nt=0;nt<4;++nt)
          acc2[mt][nt] = __builtin_amdgcn_mfma_f32_16x16x32_bf16(av[mt], bv[nt], acc2[mt][nt], 0, 0, 0);
    }
  }
  __syncthreads();

  // epilogue: + b2 + win2 residual, scatter to NCHW with unshift
  const int b  = wi >> 8;
  const int wh = (wi >> 4) & 15;
  const int ww = wi & 15;
  #pragma unroll
  for (int nt=0;nt<4;++nt){
    const int col = wv*64 + nt*16 + rowa;
    const float bias = b2[col];
    #pragma unroll
    for (int mt=0;mt<4;++mt){
      #pragma unroll
      for (int i=0;i<4;++i){
        const int row = mt*16 + kg*4 + i;
        float v = acc2[mt][nt][i] + bias + bf2f(win2[wbase + row*256 + col]);
        const int r = row >> 3, cw = row & 7;
        const int hh = (wh*8 + r + 4) & 127;
        const int wcc = (ww*8 + cw + 4) & 127;
        out[(((b<<8) + col) << 14) + hh*128 + wcc] = v;
      }
    }
  }
}

// ---------------- launch ----------------
extern "C" void kernel_launch(void* const* d_in, const int* in_sizes, int n_in,
                              void* d_out, int out_size, void* d_ws, size_t ws_size,
                              hipStream_t stream) {
  (void)in_sizes; (void)n_in; (void)out_size; (void)ws_size;
  const float* x    = (const float*)d_in[0];
  const float* ln1w = (const float*)d_in[1];
  const float* ln1b = (const float*)d_in[2];
  const float* inw  = (const float*)d_in[3];
  const float* inb  = (const float*)d_in[4];
  const float* outw = (const float*)d_in[5];
  const float* outb = (const float*)d_in[6];
  const float* ln2w = (const float*)d_in[7];
  const float* ln2b = (const float*)d_in[8];
  const float* w1f  = (const float*)d_in[9];
  const float* b1   = (const float*)d_in[10];
  const float* w2f  = (const float*)d_in[11];
  const float* b2   = (const float*)d_in[12];
  float* out = (float*)d_out;

  short* ws    = (short*)d_ws;
  short* wqkv  = ws;            // 768*256
  short* wout  = ws + 196608;   // 256*256
  short* w1b   = ws + 262144;   // 1024*256
  short* w2b   = ws + 524288;   // 256*1024
  short* win2  = ws + 786432;   // 2048*64*256 bf16

  hipLaunchKernelGGL(wconv_kernel, dim3(768),  dim3(256), 0, stream, inw,  wqkv, 196608);
  hipLaunchKernelGGL(wconv_kernel, dim3(256),  dim3(256), 0, stream, outw, wout, 65536);
  hipLaunchKernelGGL(wconv_kernel, dim3(1024), dim3(256), 0, stream, w1f,  w1b,  262144);
  hipLaunchKernelGGL(wconv_kernel, dim3(1024), dim3(256), 0, stream, w2f,  w2b,  262144);

  hipLaunchKernelGGL(swin_attn_kernel, dim3(2048), dim3(256), 0, stream,
                     x, ln1w, ln1b, inb, outb, wqkv, wout, win2);
  hipLaunchKernelGGL(swin_mlp_kernel, dim3(2048), dim3(256), 0, stream,
                     win2, ln2w, ln2b, b1, b2, w1b, w2b, out);
}